// Round 7
// baseline (183.723 us; speedup 1.0000x reference)
//
#include <hip/hip_runtime.h>

#define INV_SQRT2 0.70710678118654752440f
#define KH 0.35355339059327376220f   // INV_SQRT2 * 0.5 (output scale folded in)

// Original (non-reversed) analysis filter tables, exactly as in the reference.
// The synthesis filters are the time-reversed rows; we fold the reversal into
// the index:  out[2s+r] = sum_p ORIG[9 - r - 2p][ch] * x[(s+2-p) mod n]
__constant__ float c_first[2][10][2] = {
  { { 0.00000000000000f,  0.00000000000000f},
    {-0.08838834764832f, -0.01122679215254f},
    { 0.08838834764832f,  0.01122679215254f},
    { 0.69587998903400f,  0.08838834764832f},
    { 0.69587998903400f,  0.08838834764832f},
    { 0.08838834764832f, -0.69587998903400f},
    {-0.08838834764832f,  0.69587998903400f},
    { 0.01122679215254f, -0.08838834764832f},
    { 0.01122679215254f, -0.08838834764832f},
    { 0.00000000000000f,  0.00000000000000f} },
  { { 0.01122679215254f,  0.00000000000000f},
    { 0.01122679215254f,  0.00000000000000f},
    {-0.08838834764832f, -0.08838834764832f},
    { 0.08838834764832f, -0.08838834764832f},
    { 0.69587998903400f,  0.69587998903400f},
    { 0.69587998903400f, -0.69587998903400f},
    { 0.08838834764832f,  0.08838834764832f},
    {-0.08838834764832f,  0.08838834764832f},
    { 0.00000000000000f,  0.01122679215254f},
    { 0.00000000000000f, -0.01122679215254f} }
};

__constant__ float c_qshift[2][10][2] = {
  { { 0.03516384f,  0.00000000f},
    { 0.00000000f,  0.00000000f},
    {-0.08832942f, -0.11430184f},
    { 0.23389032f,  0.00000000f},
    { 0.76027237f,  0.58751830f},
    { 0.58751830f, -0.76027237f},
    { 0.00000000f,  0.23389032f},
    {-0.11430184f,  0.08832942f},
    { 0.00000000f,  0.00000000f},
    { 0.00000000f, -0.03516384f} },
  { { 0.00000000f, -0.03516384f},
    { 0.00000000f,  0.00000000f},
    {-0.11430184f,  0.08832942f},
    { 0.00000000f,  0.23389032f},
    { 0.58751830f, -0.76027237f},
    { 0.76027237f,  0.58751830f},
    { 0.23389032f,  0.00000000f},
    {-0.08832942f, -0.11430184f},
    { 0.00000000f,  0.00000000f},
    { 0.03516384f,  0.00000000f} }
};

// ---------------------------------------------------------------------------
// Stage 1: level-2 synthesis (Q-shift) — R3 form (L3-resident inputs).
// ---------------------------------------------------------------------------
__global__ __launch_bounds__(128) void idtcwt_stage1(
    const float* __restrict__ lows, const float* __restrict__ highs1,
    float* __restrict__ lo2)
{
  constexpr int HIN = 128, WIN = 128, C = 3, B = 16;
  constexpr int ROWF  = WIN * C;        // 384 floats per input row
  constexpr int ROWO  = 2 * WIN * C;    // 768 floats per output row
  constexpr int PLANE = HIN * WIN * C;  // 49152
  constexpr int SEG   = 16;

  const int jj = blockIdx.x * 128 + threadIdx.x;  // 0..383 = (t, c)
  const int c  = jj % 3;
  const int t  = jj / 3;                // input column 0..127
  const int z  = blockIdx.z;            // combo*16 + b
  const int combo = z >> 4;
  const int b     = z & 15;
  const int m = combo >> 1, n = combo & 1;

  const float* lo = lows + (combo * B + b) * PLANE;
  const int pa = (m == n) ? 0 : 1;
  const int pb = (m == n) ? 3 : 2;
  const float sgn = (m == 0) ? 1.0f : -1.0f;
  const int bandStride = B * PLANE;     // 786432
  const float* hA = highs1 + (pa * 3 * B + b) * PLANE;
  const float* hB = highs1 + (pb * 3 * B + b) * PLANE;

  int wc3[5];
#pragma unroll
  for (int p = 0; p < 5; ++p) {
    int w = t + 2 - p;
    if (w >= WIN) w -= WIN;
    if (w < 0)  w += WIN;
    wc3[p] = w * C + c;
  }

  float lae[5], lao[5], hae[5], hao[5];
#pragma unroll
  for (int k = 0; k < 5; ++k) { lae[k]=0.f; lao[k]=0.f; hae[k]=0.f; hao[k]=0.f; }

  const int s0 = blockIdx.y * SEG;
  float* outp = lo2 + (combo * B + b) * (4 * PLANE);

#pragma unroll 1
  for (int ui = 0; ui < SEG + 4; ++ui) {
    const int u  = (s0 - 2 + ui) & (HIN - 1);
#pragma unroll
    for (int k = 0; k < 4; ++k) { lae[k]=lae[k+1]; lao[k]=lao[k+1]; hae[k]=hae[k+1]; hao[k]=hao[k+1]; }
    const int rb = u * ROWF;

    float rl[5], rA[3][5], rB[3][5];
#pragma unroll
    for (int p = 0; p < 5; ++p) {
      const int idx = rb + wc3[p];
      rl[p]    = lo[idx];
      rA[0][p] = hA[idx];
      rB[0][p] = hB[idx];
      rA[1][p] = hA[idx +   bandStride];
      rB[1][p] = hB[idx +   bandStride];
      rA[2][p] = hA[idx + 2*bandStride];
      rB[2][p] = hB[idx + 2*bandStride];
    }

    float aLe=0.f, aLo=0.f, aHe=0.f, aHo=0.f;
#pragma unroll
    for (int p = 0; p < 5; ++p) {
      const float lv  = rl[p];
      const float lhv = (rA[0][p] + sgn * rB[0][p]) * INV_SQRT2;
      const float hlv = (rA[1][p] + sgn * rB[1][p]) * INV_SQRT2;
      const float hhv = (rA[2][p] + sgn * rB[2][p]) * INV_SQRT2;
      const float ce0 = c_qshift[n][9 - 2*p][0], ce1 = c_qshift[n][9 - 2*p][1];
      const float co0 = c_qshift[n][8 - 2*p][0], co1 = c_qshift[n][8 - 2*p][1];
      aLe += ce0 * lv  + ce1 * lhv;
      aLo += co0 * lv  + co1 * lhv;
      aHe += ce0 * hlv + ce1 * hhv;
      aHo += co0 * hlv + co1 * hhv;
    }
    lae[4]=aLe; lao[4]=aLo; hae[4]=aHe; hao[4]=aHo;

    if (ui >= 4) {
      const int s = s0 + ui - 4;
      float o00=0.f, o01=0.f, o10=0.f, o11=0.f;
#pragma unroll
      for (int p = 0; p < 5; ++p) {
        const float f0l = c_qshift[m][9 - 2*p][0], f0h = c_qshift[m][9 - 2*p][1];
        const float f1l = c_qshift[m][8 - 2*p][0], f1h = c_qshift[m][8 - 2*p][1];
        o00 += f0l*lae[4-p] + f0h*hae[4-p];
        o01 += f0l*lao[4-p] + f0h*hao[4-p];
        o10 += f1l*lae[4-p] + f1h*hae[4-p];
        o11 += f1l*lao[4-p] + f1h*hao[4-p];
      }
      float* q = outp + (2*s) * ROWO + (2*t) * C + c;
      q[0]        = o00;
      q[C]        = o01;
      q[ROWO]     = o10;
      q[ROWO + C] = o11;
    }
  }
}

// ---------------------------------------------------------------------------
// Stage 2: LDS row-staged, wide ds ops, 2-DEEP register prefetch + counted
// vmcnt + PRE-BUTTERFLIED staging.
// R7 changes vs R6 (88us, no pipe >50%):
//  - two reg sets GA/GB: loads for row i+2 issue during compute(i); ds_write
//    of row i+1 (other set) only needs the OLDER loads -> compiler emits a
//    counted s_waitcnt vmcnt(~16), not vmcnt(0). Each load gets ~2 compute
//    phases of latency cover. Phase parity static via 2-phase unroll.
//  - butterflies (x00+-x11)*K computed ONCE at stage time on registers (was
//    recomputed on every tap read = 5x); output *0.5 folded into stage
//    constants. ~-25% VALU in the col pass.
// LDS layout [slot][16 floats @ pitch 20]: conflict-free b128 (R6, proven).
// ---------------------------------------------------------------------------
__global__ __launch_bounds__(256, 3) void idtcwt_stage2(
    const float* __restrict__ lo2, const float* __restrict__ highs0,
    float* __restrict__ out)
{
  constexpr int HIN = 256, WIN = 256, C = 3, B = 16;
  constexpr int ROWF  = WIN * C;        // 768 floats per input row
  constexpr int ROWO  = 2 * WIN * C;    // 1536
  constexpr int PLANE = HIN * WIN * C;  // 196608
  constexpr int OPLANE = 512 * 512 * C; // 786432
  constexpr int SEG   = 16;
  constexpr int NI    = SEG + 4;        // 20 row phases
  constexpr int PITCH = 5;              // float4s per slot
  constexpr int BUFV4 = 272 * PITCH;

  __shared__ float4 lds4[2 * BUFV4];    // 43,520 B -> 3 blocks/CU

  const int tid = threadIdx.x;
  const int jj  = blockIdx.x * 256 + tid;
  const int c   = jj % 3;
  const int t   = jj / 3;
  const int b   = blockIdx.z;

  const int bandStride = B * PLANE;
  const float* a0  = lo2 + (0 * B + b) * PLANE;
  const float* a1  = lo2 + (1 * B + b) * PLANE;
  const float* a2  = lo2 + (2 * B + b) * PLANE;
  const float* a3  = lo2 + (3 * B + b) * PLANE;
  const float* h00b0 = highs0 + (0 * 3 * B + b) * PLANE;
  const float* h01b0 = highs0 + (1 * 3 * B + b) * PLANE;
  const float* h10b0 = highs0 + (2 * 3 * B + b) * PLANE;
  const float* h11b0 = highs0 + (3 * 3 * B + b) * PLANE;
  const float* h00b1 = h00b0 + bandStride;
  const float* h01b1 = h01b0 + bandStride;
  const float* h10b1 = h10b0 + bandStride;
  const float* h11b1 = h11b0 + bandStride;
  const float* h00b2 = h00b0 + 2*bandStride;
  const float* h01b2 = h01b0 + 2*bandStride;
  const float* h10b2 = h10b0 + 2*bandStride;
  const float* h11b2 = h11b0 + 2*bandStride;

  int j1 = jj - 6;   if (j1 < 0)     j1 += ROWF;   // slot tid
  int j2 = jj + 250; if (j2 >= ROWF) j2 -= ROWF;   // slot 256+tid (tid<12)
  const bool halo = (tid < 12);

  float wla0e[5], wla0o[5], wla1e[5], wla1o[5];
  float wha0e[5], wha0o[5], wha1e[5], wha1o[5];
#pragma unroll
  for (int k = 0; k < 5; ++k) {
    wla0e[k]=0.f; wla0o[k]=0.f; wla1e[k]=0.f; wla1o[k]=0.f;
    wha0e[k]=0.f; wha0o[k]=0.f; wha1e[k]=0.f; wha1o[k]=0.f;
  }

  const int s0 = blockIdx.y * SEG;
  float* outb = out + b * OPLANE;

  float4 GA0,GA1,GA2,GA3, HA0,HA1,HA2,HA3;   // prefetch set A
  float4 GB0,GB1,GB2,GB3, HB0,HB1,HB2,HB3;   // prefetch set B

  auto LOADR = [&](int I, float4& g0, float4& g1, float4& g2, float4& g3,
                          float4& h0, float4& h1, float4& h2, float4& h3) {
    const int rb = ((s0 - 2 + I) & (HIN - 1)) * ROWF;
    const int o1 = rb + j1;
    g0 = make_float4(a0[o1], a1[o1], a2[o1], a3[o1]);
    g1 = make_float4(h00b0[o1], h11b0[o1], h01b0[o1], h10b0[o1]);
    g2 = make_float4(h00b1[o1], h11b1[o1], h01b1[o1], h10b1[o1]);
    g3 = make_float4(h00b2[o1], h11b2[o1], h01b2[o1], h10b2[o1]);
    if (halo) {
      const int o2 = rb + j2;
      h0 = make_float4(a0[o2], a1[o2], a2[o2], a3[o2]);
      h1 = make_float4(h00b0[o2], h11b0[o2], h01b0[o2], h10b0[o2]);
      h2 = make_float4(h00b1[o2], h11b1[o2], h01b1[o2], h10b1[o2]);
      h3 = make_float4(h00b2[o2], h11b2[o2], h01b2[o2], h10b2[o2]);
    }
  };

  // pre-butterfly + 0.5-fold, then 4x ds_write_b128
  auto WRITER = [&](float4* dst,
                    const float4& g0, const float4& g1, const float4& g2, const float4& g3,
                    const float4& h0, const float4& h1, const float4& h2, const float4& h3) {
    float4* wp = dst + tid * PITCH;
    wp[0] = make_float4(g0.x*0.5f, g0.y*0.5f, g0.z*0.5f, g0.w*0.5f);
    wp[1] = make_float4((g1.x+g1.y)*KH, (g1.x-g1.y)*KH, (g1.z+g1.w)*KH, (g1.z-g1.w)*KH);
    wp[2] = make_float4((g2.x+g2.y)*KH, (g2.x-g2.y)*KH, (g2.z+g2.w)*KH, (g2.z-g2.w)*KH);
    wp[3] = make_float4((g3.x+g3.y)*KH, (g3.x-g3.y)*KH, (g3.z+g3.w)*KH, (g3.z-g3.w)*KH);
    if (halo) {
      float4* wq = dst + (256 + tid) * PITCH;
      wq[0] = make_float4(h0.x*0.5f, h0.y*0.5f, h0.z*0.5f, h0.w*0.5f);
      wq[1] = make_float4((h1.x+h1.y)*KH, (h1.x-h1.y)*KH, (h1.z+h1.w)*KH, (h1.z-h1.w)*KH);
      wq[2] = make_float4((h2.x+h2.y)*KH, (h2.x-h2.y)*KH, (h2.z+h2.w)*KH, (h2.z-h2.w)*KH);
      wq[3] = make_float4((h3.x+h3.y)*KH, (h3.x-h3.y)*KH, (h3.z+h3.w)*KH, (h3.z-h3.w)*KH);
    }
  };

  auto PHASE = [&](int I, const float4* cur) {
    // ---- column pass: staged values are pre-butterflied & 0.5-scaled ----
    float A0e=0.f,A0o=0.f,A1e=0.f,A1o=0.f, H0e=0.f,H0o=0.f,H1e=0.f,H1o=0.f;
#pragma unroll
    for (int p = 0; p < 5; ++p) {
      const float4* qp = cur + (tid + (12 - 3*p)) * PITCH;
      const float4 q0 = qp[0], q1 = qp[1], q2 = qp[2], q3 = qp[3];
      const float a0e = c_first[0][9-2*p][0], a0o = c_first[0][8-2*p][0];
      const float b0e = c_first[0][9-2*p][1], b0o = c_first[0][8-2*p][1];
      const float a1e = c_first[1][9-2*p][0], a1o = c_first[1][8-2*p][0];
      const float b1e = c_first[1][9-2*p][1], b1o = c_first[1][8-2*p][1];
      // lo2 terms (q0 = 0.5*(v00,v01,v10,v11))
      A0e += a0e*q0.x + a1e*q0.y;   A0o += a0o*q0.x + a1o*q0.y;
      A1e += a0e*q0.z + a1e*q0.w;   A1o += a0o*q0.z + a1o*q0.w;
      // LH band: q1 = (s1,d1,s2,d2)
      A0e += b0e*q1.x + b1e*q1.z;   A0o += b0o*q1.x + b1o*q1.z;
      A1e += b0e*q1.w + b1e*q1.y;   A1o += b0o*q1.w + b1o*q1.y;
      // HL band
      H0e += a0e*q2.x + a1e*q2.z;   H0o += a0o*q2.x + a1o*q2.z;
      H1e += a0e*q2.w + a1e*q2.y;   H1o += a0o*q2.w + a1o*q2.y;
      // HH band
      H0e += b0e*q3.x + b1e*q3.z;   H0o += b0o*q3.x + b1o*q3.z;
      H1e += b0e*q3.w + b1e*q3.y;   H1o += b0o*q3.w + b1o*q3.y;
    }
    // shift windows, append
#pragma unroll
    for (int k = 0; k < 4; ++k) {
      wla0e[k]=wla0e[k+1]; wla0o[k]=wla0o[k+1]; wla1e[k]=wla1e[k+1]; wla1o[k]=wla1o[k+1];
      wha0e[k]=wha0e[k+1]; wha0o[k]=wha0o[k+1]; wha1e[k]=wha1e[k+1]; wha1o[k]=wha1o[k+1];
    }
    wla0e[4]=A0e; wla0o[4]=A0o; wla1e[4]=A1e; wla1o[4]=A1o;
    wha0e[4]=H0e; wha0o[4]=H0o; wha1e[4]=H1e; wha1o[4]=H1o;

    if (I >= 4) {
      const int s = s0 + I - 4;
      float o00=0.f, o01=0.f, o10=0.f, o11=0.f;
#pragma unroll
      for (int p = 0; p < 5; ++p) {
        const float f00 = c_first[0][9-2*p][0], g00 = c_first[0][9-2*p][1];
        const float f01 = c_first[0][8-2*p][0], g01 = c_first[0][8-2*p][1];
        const float f10 = c_first[1][9-2*p][0], g10 = c_first[1][9-2*p][1];
        const float f11 = c_first[1][8-2*p][0], g11 = c_first[1][8-2*p][1];
        o00 += f00*wla0e[4-p] + g00*wha0e[4-p] + f10*wla1e[4-p] + g10*wha1e[4-p];
        o01 += f00*wla0o[4-p] + g00*wha0o[4-p] + f10*wla1o[4-p] + g10*wha1o[4-p];
        o10 += f01*wla0e[4-p] + g01*wha0e[4-p] + f11*wla1e[4-p] + g11*wha1e[4-p];
        o11 += f01*wla0o[4-p] + g01*wha0o[4-p] + f11*wla1o[4-p] + g11*wha1o[4-p];
      }
      float* q = outb + (2*s) * ROWO + (2*t) * C + c;
      q[0]        = o00;   // 0.5 folded into staging
      q[C]        = o01;
      q[ROWO]     = o10;
      q[ROWO + C] = o11;
    }
  };

  float4* cur = lds4;
  float4* nxt = lds4 + BUFV4;

  // ---- prologue: rows 0,1 into regs; row 0 -> LDS ----
  LOADR(0, GA0,GA1,GA2,GA3, HA0,HA1,HA2,HA3);
  LOADR(1, GB0,GB1,GB2,GB3, HB0,HB1,HB2,HB3);
  WRITER(cur, GA0,GA1,GA2,GA3, HA0,HA1,HA2,HA3);   // waits only set-A loads
  __syncthreads();

#pragma unroll 1
  for (int io = 0; io < NI/2; ++io) {
    { // phase I = 2io (even): issue -> A, write B
      const int I = 2*io;
      if (I + 2 < NI) {
        LOADR(I+2, GA0,GA1,GA2,GA3, HA0,HA1,HA2,HA3);
        __builtin_amdgcn_sched_barrier(0);
      }
      PHASE(I, cur);
      if (I + 1 < NI) WRITER(nxt, GB0,GB1,GB2,GB3, HB0,HB1,HB2,HB3);
      __syncthreads();
      float4* tmp = cur; cur = nxt; nxt = tmp;
    }
    { // phase I = 2io+1 (odd): issue -> B, write A
      const int I = 2*io + 1;
      if (I + 2 < NI) {
        LOADR(I+2, GB0,GB1,GB2,GB3, HB0,HB1,HB2,HB3);
        __builtin_amdgcn_sched_barrier(0);
      }
      PHASE(I, cur);
      if (I + 1 < NI) WRITER(nxt, GA0,GA1,GA2,GA3, HA0,HA1,HA2,HA3);
      __syncthreads();
      float4* tmp = cur; cur = nxt; nxt = tmp;
    }
  }
}

extern "C" void kernel_launch(void* const* d_in, const int* in_sizes, int n_in,
                              void* d_out, int out_size, void* d_ws, size_t ws_size,
                              hipStream_t stream) {
  const float* highs0 = (const float*)d_in[0];  // (2,2,3,16,256,256,3)
  const float* highs1 = (const float*)d_in[1];  // (2,2,3,16,128,128,3)
  const float* lows   = (const float*)d_in[2];  // (2,2,16,128,128,3)
  float* out = (float*)d_out;                   // (16,512,512,3)
  float* lo2 = (float*)d_ws;                    // 50.3 MB

  dim3 b1(128), g1(3, 8, 64);
  hipLaunchKernelGGL(idtcwt_stage1, g1, b1, 0, stream, lows, highs1, lo2);

  dim3 b2(256), g2(3, 16, 16);
  hipLaunchKernelGGL(idtcwt_stage2, g2, b2, 0, stream, lo2, highs0, out);
}

// Round 8
// 108.975 us; speedup vs baseline: 1.6859x; 1.6859x over previous
//
#include <hip/hip_runtime.h>

#define INV_SQRT2 0.70710678118654752440f
#define KH 0.35355339059327376220f   // INV_SQRT2 * 0.5 (output scale folded in)

// Stage-2 (first-stage) filter table as constexpr: all accesses use
// compile-time indices after unroll, so coefficients fold to immediates and
// the structural ZEROS (each coeff column is 0 at exactly one of 5 taps)
// eliminate 20% of all FMAs at compile time. (__constant__ cannot fold.)
constexpr float c_first[2][10][2] = {
  { { 0.00000000000000f,  0.00000000000000f},
    {-0.08838834764832f, -0.01122679215254f},
    { 0.08838834764832f,  0.01122679215254f},
    { 0.69587998903400f,  0.08838834764832f},
    { 0.69587998903400f,  0.08838834764832f},
    { 0.08838834764832f, -0.69587998903400f},
    {-0.08838834764832f,  0.69587998903400f},
    { 0.01122679215254f, -0.08838834764832f},
    { 0.01122679215254f, -0.08838834764832f},
    { 0.00000000000000f,  0.00000000000000f} },
  { { 0.01122679215254f,  0.00000000000000f},
    { 0.01122679215254f,  0.00000000000000f},
    {-0.08838834764832f, -0.08838834764832f},
    { 0.08838834764832f, -0.08838834764832f},
    { 0.69587998903400f,  0.69587998903400f},
    { 0.69587998903400f, -0.69587998903400f},
    { 0.08838834764832f,  0.08838834764832f},
    {-0.08838834764832f,  0.08838834764832f},
    { 0.00000000000000f,  0.01122679215254f},
    { 0.00000000000000f, -0.01122679215254f} }
};

// Stage-1 table stays __constant__: its [n]/[m] indices are runtime-uniform.
__constant__ float c_qshift[2][10][2] = {
  { { 0.03516384f,  0.00000000f},
    { 0.00000000f,  0.00000000f},
    {-0.08832942f, -0.11430184f},
    { 0.23389032f,  0.00000000f},
    { 0.76027237f,  0.58751830f},
    { 0.58751830f, -0.76027237f},
    { 0.00000000f,  0.23389032f},
    {-0.11430184f,  0.08832942f},
    { 0.00000000f,  0.00000000f},
    { 0.00000000f, -0.03516384f} },
  { { 0.00000000f, -0.03516384f},
    { 0.00000000f,  0.00000000f},
    {-0.11430184f,  0.08832942f},
    { 0.00000000f,  0.23389032f},
    { 0.58751830f, -0.76027237f},
    { 0.76027237f,  0.58751830f},
    { 0.23389032f,  0.00000000f},
    {-0.08832942f, -0.11430184f},
    { 0.00000000f,  0.00000000f},
    { 0.03516384f,  0.00000000f} }
};

// ---------------------------------------------------------------------------
// Stage 1: level-2 synthesis (Q-shift) — R3 form (L3-resident inputs, ~9us).
// ---------------------------------------------------------------------------
__global__ __launch_bounds__(128) void idtcwt_stage1(
    const float* __restrict__ lows, const float* __restrict__ highs1,
    float* __restrict__ lo2)
{
  constexpr int HIN = 128, WIN = 128, C = 3, B = 16;
  constexpr int ROWF  = WIN * C;        // 384 floats per input row
  constexpr int ROWO  = 2 * WIN * C;    // 768 floats per output row
  constexpr int PLANE = HIN * WIN * C;  // 49152
  constexpr int SEG   = 16;

  const int jj = blockIdx.x * 128 + threadIdx.x;  // 0..383 = (t, c)
  const int c  = jj % 3;
  const int t  = jj / 3;                // input column 0..127
  const int z  = blockIdx.z;            // combo*16 + b
  const int combo = z >> 4;
  const int b     = z & 15;
  const int m = combo >> 1, n = combo & 1;

  const float* lo = lows + (combo * B + b) * PLANE;
  const int pa = (m == n) ? 0 : 1;
  const int pb = (m == n) ? 3 : 2;
  const float sgn = (m == 0) ? 1.0f : -1.0f;
  const int bandStride = B * PLANE;     // 786432
  const float* hA = highs1 + (pa * 3 * B + b) * PLANE;
  const float* hB = highs1 + (pb * 3 * B + b) * PLANE;

  int wc3[5];
#pragma unroll
  for (int p = 0; p < 5; ++p) {
    int w = t + 2 - p;
    if (w >= WIN) w -= WIN;
    if (w < 0)  w += WIN;
    wc3[p] = w * C + c;
  }

  float lae[5], lao[5], hae[5], hao[5];
#pragma unroll
  for (int k = 0; k < 5; ++k) { lae[k]=0.f; lao[k]=0.f; hae[k]=0.f; hao[k]=0.f; }

  const int s0 = blockIdx.y * SEG;
  float* outp = lo2 + (combo * B + b) * (4 * PLANE);

#pragma unroll 1
  for (int ui = 0; ui < SEG + 4; ++ui) {
    const int u  = (s0 - 2 + ui) & (HIN - 1);
#pragma unroll
    for (int k = 0; k < 4; ++k) { lae[k]=lae[k+1]; lao[k]=lao[k+1]; hae[k]=hae[k+1]; hao[k]=hao[k+1]; }
    const int rb = u * ROWF;

    float rl[5], rA[3][5], rB[3][5];
#pragma unroll
    for (int p = 0; p < 5; ++p) {
      const int idx = rb + wc3[p];
      rl[p]    = lo[idx];
      rA[0][p] = hA[idx];
      rB[0][p] = hB[idx];
      rA[1][p] = hA[idx +   bandStride];
      rB[1][p] = hB[idx +   bandStride];
      rA[2][p] = hA[idx + 2*bandStride];
      rB[2][p] = hB[idx + 2*bandStride];
    }

    float aLe=0.f, aLo=0.f, aHe=0.f, aHo=0.f;
#pragma unroll
    for (int p = 0; p < 5; ++p) {
      const float lv  = rl[p];
      const float lhv = (rA[0][p] + sgn * rB[0][p]) * INV_SQRT2;
      const float hlv = (rA[1][p] + sgn * rB[1][p]) * INV_SQRT2;
      const float hhv = (rA[2][p] + sgn * rB[2][p]) * INV_SQRT2;
      const float ce0 = c_qshift[n][9 - 2*p][0], ce1 = c_qshift[n][9 - 2*p][1];
      const float co0 = c_qshift[n][8 - 2*p][0], co1 = c_qshift[n][8 - 2*p][1];
      aLe += ce0 * lv  + ce1 * lhv;
      aLo += co0 * lv  + co1 * lhv;
      aHe += ce0 * hlv + ce1 * hhv;
      aHo += co0 * hlv + co1 * hhv;
    }
    lae[4]=aLe; lao[4]=aLo; hae[4]=aHe; hao[4]=aHo;

    if (ui >= 4) {
      const int s = s0 + ui - 4;
      float o00=0.f, o01=0.f, o10=0.f, o11=0.f;
#pragma unroll
      for (int p = 0; p < 5; ++p) {
        const float f0l = c_qshift[m][9 - 2*p][0], f0h = c_qshift[m][9 - 2*p][1];
        const float f1l = c_qshift[m][8 - 2*p][0], f1h = c_qshift[m][8 - 2*p][1];
        o00 += f0l*lae[4-p] + f0h*hae[4-p];
        o01 += f0l*lao[4-p] + f0h*hao[4-p];
        o10 += f1l*lae[4-p] + f1h*hae[4-p];
        o11 += f1l*lao[4-p] + f1h*hao[4-p];
      }
      float* q = outp + (2*s) * ROWO + (2*t) * C + c;
      q[0]        = o00;
      q[C]        = o01;
      q[ROWO]     = o10;
      q[ROWO + C] = o11;
    }
  }
}

// ---------------------------------------------------------------------------
// Stage 2: R6 structure (proven 88us) + two instruction-count cuts:
//  - PRE-BUTTERFLIED staging: (x00 +/- x11)*KH computed once at ds_write time
//    (was recomputed on every tap read = 5x); output *0.5 folded in. Numerics
//    validated by R7 (passed). Plain named float4 vars, NO lambdas (R7's
//    lambda/aggregate plumbing sent prefetch regs to scratch: VGPR=84,
//    WRITE_SIZE +15MB, 160us).
//  - constexpr c_first: coefficients become immediates; zero taps (1 of 5 in
//    every coeff column) fold away 20% of FMAs; no SMEM coeff loads.
// LDS layout [slot][16 floats @ pitch 20]: conflict-free b128 (R6, proven).
// ---------------------------------------------------------------------------
__global__ __launch_bounds__(256, 3) void idtcwt_stage2(
    const float* __restrict__ lo2, const float* __restrict__ highs0,
    float* __restrict__ out)
{
  constexpr int HIN = 256, WIN = 256, C = 3, B = 16;
  constexpr int ROWF  = WIN * C;        // 768 floats per input row
  constexpr int ROWO  = 2 * WIN * C;    // 1536
  constexpr int PLANE = HIN * WIN * C;  // 196608
  constexpr int OPLANE = 512 * 512 * C; // 786432
  constexpr int SEG   = 16;
  constexpr int NI    = SEG + 4;        // 20 iterations
  constexpr int PITCH = 5;              // float4s per slot (16 arrays + pad)
  constexpr int BUFV4 = 272 * PITCH;    // 1360 float4 per buffer

  __shared__ float4 lds4[2 * BUFV4];    // 43,520 B -> 3 blocks/CU

  const int tid = threadIdx.x;
  const int jj  = blockIdx.x * 256 + tid;  // 0..767 = (t,c)
  const int c   = jj % 3;
  const int t   = jj / 3;
  const int b   = blockIdx.z;

  const int bandStride = B * PLANE;
  const float* a0  = lo2 + (0 * B + b) * PLANE;           // l00
  const float* a1  = lo2 + (1 * B + b) * PLANE;           // l01
  const float* a2  = lo2 + (2 * B + b) * PLANE;           // l10
  const float* a3  = lo2 + (3 * B + b) * PLANE;           // l11
  const float* h00b0 = highs0 + (0 * 3 * B + b) * PLANE;
  const float* h01b0 = highs0 + (1 * 3 * B + b) * PLANE;
  const float* h10b0 = highs0 + (2 * 3 * B + b) * PLANE;
  const float* h11b0 = highs0 + (3 * 3 * B + b) * PLANE;
  const float* h00b1 = h00b0 + bandStride;
  const float* h01b1 = h01b0 + bandStride;
  const float* h10b1 = h10b0 + bandStride;
  const float* h11b1 = h11b0 + bandStride;
  const float* h00b2 = h00b0 + 2*bandStride;
  const float* h01b2 = h01b0 + 2*bandStride;
  const float* h10b2 = h10b0 + 2*bandStride;
  const float* h11b2 = h11b0 + 2*bandStride;

  // staging source offsets (slot k holds global jj' = 256*blockIdx.x - 6 + k)
  int j1 = jj - 6;   if (j1 < 0)     j1 += ROWF;   // slot tid
  int j2 = jj + 250; if (j2 >= ROWF) j2 -= ROWF;   // slot 256+tid (tid<12)
  const bool halo = (tid < 12);

  // circular window, all indices static after unroll
  float wla0e[5], wla0o[5], wla1e[5], wla1o[5];
  float wha0e[5], wha0o[5], wha1e[5], wha1o[5];

  const int s0 = blockIdx.y * SEG;
  float* outb = out + b * OPLANE;

  float4 G0, G1, G2, G3, Hh0, Hh1, Hh2, Hh3;

#define S2_LOAD(I)                                                           \
  {                                                                          \
    const int rb_ = ((s0 - 2 + (I)) & (HIN - 1)) * ROWF;                     \
    const int o1_ = rb_ + j1;                                                \
    G0 = make_float4(a0[o1_], a1[o1_], a2[o1_], a3[o1_]);                    \
    G1 = make_float4(h00b0[o1_], h11b0[o1_], h01b0[o1_], h10b0[o1_]);        \
    G2 = make_float4(h00b1[o1_], h11b1[o1_], h01b1[o1_], h10b1[o1_]);        \
    G3 = make_float4(h00b2[o1_], h11b2[o1_], h01b2[o1_], h10b2[o1_]);        \
    if (halo) {                                                              \
      const int o2_ = rb_ + j2;                                              \
      Hh0 = make_float4(a0[o2_], a1[o2_], a2[o2_], a3[o2_]);                 \
      Hh1 = make_float4(h00b0[o2_], h11b0[o2_], h01b0[o2_], h10b0[o2_]);     \
      Hh2 = make_float4(h00b1[o2_], h11b1[o2_], h01b1[o2_], h10b1[o2_]);     \
      Hh3 = make_float4(h00b2[o2_], h11b2[o2_], h01b2[o2_], h10b2[o2_]);     \
    }                                                                        \
  }

// pre-butterfly + 0.5-fold, then 4x ds_write_b128. (h00,h11,h01,h10) ->
// (s1,d1,s2,d2) with s=(x00+x11)*KH, d=(x00-x11)*KH etc.
#define S2_WRITE(DST)                                                        \
  {                                                                          \
    float4* w_ = (DST) + tid * PITCH;                                        \
    w_[0] = make_float4(G0.x*0.5f, G0.y*0.5f, G0.z*0.5f, G0.w*0.5f);         \
    w_[1] = make_float4((G1.x+G1.y)*KH, (G1.x-G1.y)*KH,                      \
                        (G1.z+G1.w)*KH, (G1.z-G1.w)*KH);                     \
    w_[2] = make_float4((G2.x+G2.y)*KH, (G2.x-G2.y)*KH,                      \
                        (G2.z+G2.w)*KH, (G2.z-G2.w)*KH);                     \
    w_[3] = make_float4((G3.x+G3.y)*KH, (G3.x-G3.y)*KH,                      \
                        (G3.z+G3.w)*KH, (G3.z-G3.w)*KH);                     \
    if (halo) {                                                              \
      float4* w2_ = (DST) + (256 + tid) * PITCH;                             \
      w2_[0] = make_float4(Hh0.x*0.5f, Hh0.y*0.5f, Hh0.z*0.5f, Hh0.w*0.5f);  \
      w2_[1] = make_float4((Hh1.x+Hh1.y)*KH, (Hh1.x-Hh1.y)*KH,               \
                           (Hh1.z+Hh1.w)*KH, (Hh1.z-Hh1.w)*KH);              \
      w2_[2] = make_float4((Hh2.x+Hh2.y)*KH, (Hh2.x-Hh2.y)*KH,               \
                           (Hh2.z+Hh2.w)*KH, (Hh2.z-Hh2.w)*KH);              \
      w2_[3] = make_float4((Hh3.x+Hh3.y)*KH, (Hh3.x-Hh3.y)*KH,               \
                           (Hh3.z+Hh3.w)*KH, (Hh3.z-Hh3.w)*KH);              \
    }                                                                        \
  }

  float4* cur = lds4;
  float4* nxt = lds4 + BUFV4;

  // ---- prologue: stage row i=0 ----
  S2_LOAD(0);
  S2_WRITE(cur);
  __syncthreads();

#pragma unroll 1
  for (int uo = 0; uo < 4; ++uo) {
#pragma unroll
    for (int k = 0; k < 5; ++k) {
      const int i = uo * 5 + k;           // window slot = k (static)

      if (i < NI - 1) {
        S2_LOAD(i + 1);
        __builtin_amdgcn_sched_barrier(0);  // keep loads above the compute
      }

      // ---- column pass from cur: taps at slot tid + 12 - 3p ----
      // staged: q0 = 0.5*(v00,v01,v10,v11); q1..q3 = (s1,d1,s2,d2) per band
      float A0e=0.f,A0o=0.f,A1e=0.f,A1o=0.f, H0e=0.f,H0o=0.f,H1e=0.f,H1o=0.f;
#pragma unroll
      for (int p = 0; p < 5; ++p) {
        const float4* qp = cur + (tid + (12 - 3*p)) * PITCH;
        const float4 q0 = qp[0], q1 = qp[1], q2 = qp[2], q3 = qp[3];
        const float a0e = c_first[0][9-2*p][0], a0o = c_first[0][8-2*p][0];
        const float b0e = c_first[0][9-2*p][1], b0o = c_first[0][8-2*p][1];
        const float a1e = c_first[1][9-2*p][0], a1o = c_first[1][8-2*p][0];
        const float b1e = c_first[1][9-2*p][1], b1o = c_first[1][8-2*p][1];
        // lo2 terms
        A0e += a0e*q0.x + a1e*q0.y;   A0o += a0o*q0.x + a1o*q0.y;
        A1e += a0e*q0.z + a1e*q0.w;   A1o += a0o*q0.z + a1o*q0.w;
        // LH band: q1 = (s1,d1,s2,d2)
        A0e += b0e*q1.x + b1e*q1.z;   A0o += b0o*q1.x + b1o*q1.z;
        A1e += b0e*q1.w + b1e*q1.y;   A1o += b0o*q1.w + b1o*q1.y;
        // HL band
        H0e += a0e*q2.x + a1e*q2.z;   H0o += a0o*q2.x + a1o*q2.z;
        H1e += a0e*q2.w + a1e*q2.y;   H1o += a0o*q2.w + a1o*q2.y;
        // HH band
        H0e += b0e*q3.x + b1e*q3.z;   H0o += b0o*q3.x + b1o*q3.z;
        H1e += b0e*q3.w + b1e*q3.y;   H1o += b0o*q3.w + b1o*q3.y;
      }
      wla0e[k]=A0e; wla0o[k]=A0o; wla1e[k]=A1e; wla1o[k]=A1o;
      wha0e[k]=H0e; wha0o[k]=H0o; wha1e[k]=H1e; wha1o[k]=H1o;

      if (i >= 4) {
        const int s = s0 + i - 4;
        float o00=0.f, o01=0.f, o10=0.f, o11=0.f;
#pragma unroll
        for (int p = 0; p < 5; ++p) {
          const int kk = (k - p + 5) % 5;   // static
          const float f00 = c_first[0][9-2*p][0], g00 = c_first[0][9-2*p][1];
          const float f01 = c_first[0][8-2*p][0], g01 = c_first[0][8-2*p][1];
          const float f10 = c_first[1][9-2*p][0], g10 = c_first[1][9-2*p][1];
          const float f11 = c_first[1][8-2*p][0], g11 = c_first[1][8-2*p][1];
          o00 += f00*wla0e[kk] + g00*wha0e[kk] + f10*wla1e[kk] + g10*wha1e[kk];
          o01 += f00*wla0o[kk] + g00*wha0o[kk] + f10*wla1o[kk] + g10*wha1o[kk];
          o10 += f01*wla0e[kk] + g01*wha0e[kk] + f11*wla1e[kk] + g11*wha1e[kk];
          o11 += f01*wla0o[kk] + g01*wha0o[kk] + f11*wla1o[kk] + g11*wha1o[kk];
        }
        float* q = outb + (2*s) * ROWO + (2*t) * C + c;
        q[0]        = o00;   // 0.5 folded into staging
        q[C]        = o01;
        q[ROWO]     = o10;
        q[ROWO + C] = o11;
      }

      if (i < NI - 1) {
        S2_WRITE(nxt);                    // vmcnt wait lands here
      }
      __syncthreads();
      { float4* tmp = cur; cur = nxt; nxt = tmp; }
    }
  }
#undef S2_LOAD
#undef S2_WRITE
}

extern "C" void kernel_launch(void* const* d_in, const int* in_sizes, int n_in,
                              void* d_out, int out_size, void* d_ws, size_t ws_size,
                              hipStream_t stream) {
  const float* highs0 = (const float*)d_in[0];  // (2,2,3,16,256,256,3)
  const float* highs1 = (const float*)d_in[1];  // (2,2,3,16,128,128,3)
  const float* lows   = (const float*)d_in[2];  // (2,2,16,128,128,3)
  float* out = (float*)d_out;                   // (16,512,512,3)
  float* lo2 = (float*)d_ws;                    // 50.3 MB

  dim3 b1(128), g1(3, 8, 64);
  hipLaunchKernelGGL(idtcwt_stage1, g1, b1, 0, stream, lows, highs1, lo2);

  dim3 b2(256), g2(3, 16, 16);
  hipLaunchKernelGGL(idtcwt_stage2, g2, b2, 0, stream, lo2, highs0, out);
}

// Round 9
// 108.898 us; speedup vs baseline: 1.6871x; 1.0007x over previous
//
#include <hip/hip_runtime.h>

#define INV_SQRT2 0.70710678118654752440f
#define KH 0.35355339059327376220f   // INV_SQRT2 * 0.5 (output scale folded in)

// Stage-2 (first-stage) filter table as constexpr: compile-time indices after
// unroll -> coefficients fold to immediates; structural zeros kill 20% of FMAs.
constexpr float c_first[2][10][2] = {
  { { 0.00000000000000f,  0.00000000000000f},
    {-0.08838834764832f, -0.01122679215254f},
    { 0.08838834764832f,  0.01122679215254f},
    { 0.69587998903400f,  0.08838834764832f},
    { 0.69587998903400f,  0.08838834764832f},
    { 0.08838834764832f, -0.69587998903400f},
    {-0.08838834764832f,  0.69587998903400f},
    { 0.01122679215254f, -0.08838834764832f},
    { 0.01122679215254f, -0.08838834764832f},
    { 0.00000000000000f,  0.00000000000000f} },
  { { 0.01122679215254f,  0.00000000000000f},
    { 0.01122679215254f,  0.00000000000000f},
    {-0.08838834764832f, -0.08838834764832f},
    { 0.08838834764832f, -0.08838834764832f},
    { 0.69587998903400f,  0.69587998903400f},
    { 0.69587998903400f, -0.69587998903400f},
    { 0.08838834764832f,  0.08838834764832f},
    {-0.08838834764832f,  0.08838834764832f},
    { 0.00000000000000f,  0.01122679215254f},
    { 0.00000000000000f, -0.01122679215254f} }
};

// Stage-1 table stays __constant__: its [n]/[m] indices are runtime-uniform.
__constant__ float c_qshift[2][10][2] = {
  { { 0.03516384f,  0.00000000f},
    { 0.00000000f,  0.00000000f},
    {-0.08832942f, -0.11430184f},
    { 0.23389032f,  0.00000000f},
    { 0.76027237f,  0.58751830f},
    { 0.58751830f, -0.76027237f},
    { 0.00000000f,  0.23389032f},
    {-0.11430184f,  0.08832942f},
    { 0.00000000f,  0.00000000f},
    { 0.00000000f, -0.03516384f} },
  { { 0.00000000f, -0.03516384f},
    { 0.00000000f,  0.00000000f},
    {-0.11430184f,  0.08832942f},
    { 0.00000000f,  0.23389032f},
    { 0.58751830f, -0.76027237f},
    { 0.76027237f,  0.58751830f},
    { 0.23389032f,  0.00000000f},
    {-0.08832942f, -0.11430184f},
    { 0.00000000f,  0.00000000f},
    { 0.03516384f,  0.00000000f} }
};

// ---------------------------------------------------------------------------
// Stage 1: level-2 synthesis (Q-shift). R3 gather structure + KEEP-ALIVE PINS:
// asm volatile("" :: "v"(x)) after the 35-load batch makes load-sinking
// illegal -> one MLP-35 wait region per iteration instead of ~8 chunked
// round-trips (R3/R8 lesson: compiler minimizes live ranges otherwise).
// __launch_bounds__(128,3): grid supplies 6 blocks/CU x 2 waves = 3/SIMD.
// ---------------------------------------------------------------------------
__global__ __launch_bounds__(128, 3) void idtcwt_stage1(
    const float* __restrict__ lows, const float* __restrict__ highs1,
    float* __restrict__ lo2)
{
  constexpr int HIN = 128, WIN = 128, C = 3, B = 16;
  constexpr int ROWF  = WIN * C;        // 384 floats per input row
  constexpr int ROWO  = 2 * WIN * C;    // 768 floats per output row
  constexpr int PLANE = HIN * WIN * C;  // 49152
  constexpr int SEG   = 16;

  const int jj = blockIdx.x * 128 + threadIdx.x;  // 0..383 = (t, c)
  const int c  = jj % 3;
  const int t  = jj / 3;                // input column 0..127
  const int z  = blockIdx.z;            // combo*16 + b
  const int combo = z >> 4;
  const int b     = z & 15;
  const int m = combo >> 1, n = combo & 1;

  const float* lo = lows + (combo * B + b) * PLANE;
  const int pa = (m == n) ? 0 : 1;
  const int pb = (m == n) ? 3 : 2;
  const float sgn = (m == 0) ? 1.0f : -1.0f;
  const int bandStride = B * PLANE;     // 786432
  const float* hA = highs1 + (pa * 3 * B + b) * PLANE;
  const float* hB = highs1 + (pb * 3 * B + b) * PLANE;

  int wc3[5];
#pragma unroll
  for (int p = 0; p < 5; ++p) {
    int w = t + 2 - p;
    if (w >= WIN) w -= WIN;
    if (w < 0)  w += WIN;
    wc3[p] = w * C + c;
  }

  float lae[5], lao[5], hae[5], hao[5];
#pragma unroll
  for (int k = 0; k < 5; ++k) { lae[k]=0.f; lao[k]=0.f; hae[k]=0.f; hao[k]=0.f; }

  const int s0 = blockIdx.y * SEG;
  float* outp = lo2 + (combo * B + b) * (4 * PLANE);

#pragma unroll 1
  for (int ui = 0; ui < SEG + 4; ++ui) {
    const int u  = (s0 - 2 + ui) & (HIN - 1);
#pragma unroll
    for (int k = 0; k < 4; ++k) { lae[k]=lae[k+1]; lao[k]=lao[k+1]; hae[k]=hae[k+1]; hao[k]=hao[k+1]; }
    const int rb = u * ROWF;

    float rl[5], rA[3][5], rB[3][5];
#pragma unroll
    for (int p = 0; p < 5; ++p) {
      const int idx = rb + wc3[p];
      rl[p]    = lo[idx];
      rA[0][p] = hA[idx];
      rB[0][p] = hB[idx];
      rA[1][p] = hA[idx +   bandStride];
      rB[1][p] = hB[idx +   bandStride];
      rA[2][p] = hA[idx + 2*bandStride];
      rB[2][p] = hB[idx + 2*bandStride];
    }
    // keep-alive pins: forbid sinking/chunking of the 35-load batch
    asm volatile("" :: "v"(rl[0]),"v"(rl[1]),"v"(rl[2]),"v"(rl[3]),"v"(rl[4]),
                       "v"(rA[0][0]),"v"(rA[0][1]),"v"(rA[0][2]),"v"(rA[0][3]),"v"(rA[0][4]),
                       "v"(rA[1][0]),"v"(rA[1][1]),"v"(rA[1][2]),"v"(rA[1][3]),"v"(rA[1][4]));
    asm volatile("" :: "v"(rA[2][0]),"v"(rA[2][1]),"v"(rA[2][2]),"v"(rA[2][3]),"v"(rA[2][4]),
                       "v"(rB[0][0]),"v"(rB[0][1]),"v"(rB[0][2]),"v"(rB[0][3]),"v"(rB[0][4]),
                       "v"(rB[1][0]),"v"(rB[1][1]),"v"(rB[1][2]),"v"(rB[1][3]),"v"(rB[1][4]));
    asm volatile("" :: "v"(rB[2][0]),"v"(rB[2][1]),"v"(rB[2][2]),"v"(rB[2][3]),"v"(rB[2][4]));

    float aLe=0.f, aLo=0.f, aHe=0.f, aHo=0.f;
#pragma unroll
    for (int p = 0; p < 5; ++p) {
      const float lv  = rl[p];
      const float lhv = (rA[0][p] + sgn * rB[0][p]) * INV_SQRT2;
      const float hlv = (rA[1][p] + sgn * rB[1][p]) * INV_SQRT2;
      const float hhv = (rA[2][p] + sgn * rB[2][p]) * INV_SQRT2;
      const float ce0 = c_qshift[n][9 - 2*p][0], ce1 = c_qshift[n][9 - 2*p][1];
      const float co0 = c_qshift[n][8 - 2*p][0], co1 = c_qshift[n][8 - 2*p][1];
      aLe += ce0 * lv  + ce1 * lhv;
      aLo += co0 * lv  + co1 * lhv;
      aHe += ce0 * hlv + ce1 * hhv;
      aHo += co0 * hlv + co1 * hhv;
    }
    lae[4]=aLe; lao[4]=aLo; hae[4]=aHe; hao[4]=aHo;

    if (ui >= 4) {
      const int s = s0 + ui - 4;
      float o00=0.f, o01=0.f, o10=0.f, o11=0.f;
#pragma unroll
      for (int p = 0; p < 5; ++p) {
        const float f0l = c_qshift[m][9 - 2*p][0], f0h = c_qshift[m][9 - 2*p][1];
        const float f1l = c_qshift[m][8 - 2*p][0], f1h = c_qshift[m][8 - 2*p][1];
        o00 += f0l*lae[4-p] + f0h*hae[4-p];
        o01 += f0l*lao[4-p] + f0h*hao[4-p];
        o10 += f1l*lae[4-p] + f1h*hae[4-p];
        o11 += f1l*lao[4-p] + f1h*hao[4-p];
      }
      float* q = outp + (2*s) * ROWO + (2*t) * C + c;
      q[0]        = o00;
      q[C]        = o01;
      q[ROWO]     = o10;
      q[ROWO + C] = o11;
    }
  }
}

// ---------------------------------------------------------------------------
// Stage 2: R8 structure (LDS row-staged, wide ds ops, pre-butterflied staging,
// constexpr-folded coeffs) + KEEP-ALIVE PINS on the 32 prefetch floats placed
// just before S2_WRITE. R8 evidence: VGPR=68 < ~100 needed for the prefetch
// batch to stay live -> compiler sank the loads toward S2_WRITE, re-exposing
// HBM latency before every barrier. The pin makes that sinking illegal; with
// the sched_barrier(0) at top the loads get the whole compute phase of cover.
// ---------------------------------------------------------------------------
__global__ __launch_bounds__(256, 3) void idtcwt_stage2(
    const float* __restrict__ lo2, const float* __restrict__ highs0,
    float* __restrict__ out)
{
  constexpr int HIN = 256, WIN = 256, C = 3, B = 16;
  constexpr int ROWF  = WIN * C;        // 768 floats per input row
  constexpr int ROWO  = 2 * WIN * C;    // 1536
  constexpr int PLANE = HIN * WIN * C;  // 196608
  constexpr int OPLANE = 512 * 512 * C; // 786432
  constexpr int SEG   = 16;
  constexpr int NI    = SEG + 4;        // 20 iterations
  constexpr int PITCH = 5;              // float4s per slot (16 arrays + pad)
  constexpr int BUFV4 = 272 * PITCH;    // 1360 float4 per buffer

  __shared__ float4 lds4[2 * BUFV4];    // 43,520 B -> 3 blocks/CU

  const int tid = threadIdx.x;
  const int jj  = blockIdx.x * 256 + tid;  // 0..767 = (t,c)
  const int c   = jj % 3;
  const int t   = jj / 3;
  const int b   = blockIdx.z;

  const int bandStride = B * PLANE;
  const float* a0  = lo2 + (0 * B + b) * PLANE;           // l00
  const float* a1  = lo2 + (1 * B + b) * PLANE;           // l01
  const float* a2  = lo2 + (2 * B + b) * PLANE;           // l10
  const float* a3  = lo2 + (3 * B + b) * PLANE;           // l11
  const float* h00b0 = highs0 + (0 * 3 * B + b) * PLANE;
  const float* h01b0 = highs0 + (1 * 3 * B + b) * PLANE;
  const float* h10b0 = highs0 + (2 * 3 * B + b) * PLANE;
  const float* h11b0 = highs0 + (3 * 3 * B + b) * PLANE;
  const float* h00b1 = h00b0 + bandStride;
  const float* h01b1 = h01b0 + bandStride;
  const float* h10b1 = h10b0 + bandStride;
  const float* h11b1 = h11b0 + bandStride;
  const float* h00b2 = h00b0 + 2*bandStride;
  const float* h01b2 = h01b0 + 2*bandStride;
  const float* h10b2 = h10b0 + 2*bandStride;
  const float* h11b2 = h11b0 + 2*bandStride;

  // staging source offsets (slot k holds global jj' = 256*blockIdx.x - 6 + k)
  int j1 = jj - 6;   if (j1 < 0)     j1 += ROWF;   // slot tid
  int j2 = jj + 250; if (j2 >= ROWF) j2 -= ROWF;   // slot 256+tid (tid<12)
  const bool halo = (tid < 12);

  // circular window, all indices static after unroll
  float wla0e[5], wla0o[5], wla1e[5], wla1o[5];
  float wha0e[5], wha0o[5], wha1e[5], wha1o[5];

  const int s0 = blockIdx.y * SEG;
  float* outb = out + b * OPLANE;

  float4 G0, G1, G2, G3;
  float4 Hh0 = make_float4(0.f,0.f,0.f,0.f), Hh1 = Hh0, Hh2 = Hh0, Hh3 = Hh0;

#define S2_LOAD(I)                                                           \
  {                                                                          \
    const int rb_ = ((s0 - 2 + (I)) & (HIN - 1)) * ROWF;                     \
    const int o1_ = rb_ + j1;                                                \
    G0 = make_float4(a0[o1_], a1[o1_], a2[o1_], a3[o1_]);                    \
    G1 = make_float4(h00b0[o1_], h11b0[o1_], h01b0[o1_], h10b0[o1_]);        \
    G2 = make_float4(h00b1[o1_], h11b1[o1_], h01b1[o1_], h10b1[o1_]);        \
    G3 = make_float4(h00b2[o1_], h11b2[o1_], h01b2[o1_], h10b2[o1_]);        \
    if (halo) {                                                              \
      const int o2_ = rb_ + j2;                                              \
      Hh0 = make_float4(a0[o2_], a1[o2_], a2[o2_], a3[o2_]);                 \
      Hh1 = make_float4(h00b0[o2_], h11b0[o2_], h01b0[o2_], h10b0[o2_]);     \
      Hh2 = make_float4(h00b1[o2_], h11b1[o2_], h01b1[o2_], h10b1[o2_]);     \
      Hh3 = make_float4(h00b2[o2_], h11b2[o2_], h01b2[o2_], h10b2[o2_]);     \
    }                                                                        \
  }

// keep-alive: values must be in VGPRs at this point; loads cannot sink past.
#define S2_PIN()                                                             \
  asm volatile("" :: "v"(G0.x),"v"(G0.y),"v"(G0.z),"v"(G0.w),                \
                     "v"(G1.x),"v"(G1.y),"v"(G1.z),"v"(G1.w),                \
                     "v"(G2.x),"v"(G2.y),"v"(G2.z),"v"(G2.w),                \
                     "v"(G3.x),"v"(G3.y),"v"(G3.z),"v"(G3.w));               \
  asm volatile("" :: "v"(Hh0.x),"v"(Hh0.y),"v"(Hh0.z),"v"(Hh0.w),            \
                     "v"(Hh1.x),"v"(Hh1.y),"v"(Hh1.z),"v"(Hh1.w),            \
                     "v"(Hh2.x),"v"(Hh2.y),"v"(Hh2.z),"v"(Hh2.w),            \
                     "v"(Hh3.x),"v"(Hh3.y),"v"(Hh3.z),"v"(Hh3.w));

// pre-butterfly + 0.5-fold, then 4x ds_write_b128.
#define S2_WRITE(DST)                                                        \
  {                                                                          \
    float4* w_ = (DST) + tid * PITCH;                                        \
    w_[0] = make_float4(G0.x*0.5f, G0.y*0.5f, G0.z*0.5f, G0.w*0.5f);         \
    w_[1] = make_float4((G1.x+G1.y)*KH, (G1.x-G1.y)*KH,                      \
                        (G1.z+G1.w)*KH, (G1.z-G1.w)*KH);                     \
    w_[2] = make_float4((G2.x+G2.y)*KH, (G2.x-G2.y)*KH,                      \
                        (G2.z+G2.w)*KH, (G2.z-G2.w)*KH);                     \
    w_[3] = make_float4((G3.x+G3.y)*KH, (G3.x-G3.y)*KH,                      \
                        (G3.z+G3.w)*KH, (G3.z-G3.w)*KH);                     \
    if (halo) {                                                              \
      float4* w2_ = (DST) + (256 + tid) * PITCH;                             \
      w2_[0] = make_float4(Hh0.x*0.5f, Hh0.y*0.5f, Hh0.z*0.5f, Hh0.w*0.5f);  \
      w2_[1] = make_float4((Hh1.x+Hh1.y)*KH, (Hh1.x-Hh1.y)*KH,               \
                           (Hh1.z+Hh1.w)*KH, (Hh1.z-Hh1.w)*KH);              \
      w2_[2] = make_float4((Hh2.x+Hh2.y)*KH, (Hh2.x-Hh2.y)*KH,               \
                           (Hh2.z+Hh2.w)*KH, (Hh2.z-Hh2.w)*KH);              \
      w2_[3] = make_float4((Hh3.x+Hh3.y)*KH, (Hh3.x-Hh3.y)*KH,               \
                           (Hh3.z+Hh3.w)*KH, (Hh3.z-Hh3.w)*KH);              \
    }                                                                        \
  }

  float4* cur = lds4;
  float4* nxt = lds4 + BUFV4;

  // ---- prologue: stage row i=0 ----
  S2_LOAD(0);
  S2_WRITE(cur);
  __syncthreads();

#pragma unroll 1
  for (int uo = 0; uo < 4; ++uo) {
#pragma unroll
    for (int k = 0; k < 5; ++k) {
      const int i = uo * 5 + k;           // window slot = k (static)

      if (i < NI - 1) {
        S2_LOAD(i + 1);
        __builtin_amdgcn_sched_barrier(0);  // keep load issue at phase top
      }

      // ---- column pass from cur: taps at slot tid + 12 - 3p ----
      float A0e=0.f,A0o=0.f,A1e=0.f,A1o=0.f, H0e=0.f,H0o=0.f,H1e=0.f,H1o=0.f;
#pragma unroll
      for (int p = 0; p < 5; ++p) {
        const float4* qp = cur + (tid + (12 - 3*p)) * PITCH;
        const float4 q0 = qp[0], q1 = qp[1], q2 = qp[2], q3 = qp[3];
        const float a0e = c_first[0][9-2*p][0], a0o = c_first[0][8-2*p][0];
        const float b0e = c_first[0][9-2*p][1], b0o = c_first[0][8-2*p][1];
        const float a1e = c_first[1][9-2*p][0], a1o = c_first[1][8-2*p][0];
        const float b1e = c_first[1][9-2*p][1], b1o = c_first[1][8-2*p][1];
        // lo2 terms (q0 = 0.5*(v00,v01,v10,v11))
        A0e += a0e*q0.x + a1e*q0.y;   A0o += a0o*q0.x + a1o*q0.y;
        A1e += a0e*q0.z + a1e*q0.w;   A1o += a0o*q0.z + a1o*q0.w;
        // LH band: q1 = (s1,d1,s2,d2)
        A0e += b0e*q1.x + b1e*q1.z;   A0o += b0o*q1.x + b1o*q1.z;
        A1e += b0e*q1.w + b1e*q1.y;   A1o += b0o*q1.w + b1o*q1.y;
        // HL band
        H0e += a0e*q2.x + a1e*q2.z;   H0o += a0o*q2.x + a1o*q2.z;
        H1e += a0e*q2.w + a1e*q2.y;   H1o += a0o*q2.w + a1o*q2.y;
        // HH band
        H0e += b0e*q3.x + b1e*q3.z;   H0o += b0o*q3.x + b1o*q3.z;
        H1e += b0e*q3.w + b1e*q3.y;   H1o += b0o*q3.w + b1o*q3.y;
      }
      wla0e[k]=A0e; wla0o[k]=A0o; wla1e[k]=A1e; wla1o[k]=A1o;
      wha0e[k]=H0e; wha0o[k]=H0o; wha1e[k]=H1e; wha1o[k]=H1o;

      if (i >= 4) {
        const int s = s0 + i - 4;
        float o00=0.f, o01=0.f, o10=0.f, o11=0.f;
#pragma unroll
        for (int p = 0; p < 5; ++p) {
          const int kk = (k - p + 5) % 5;   // static
          const float f00 = c_first[0][9-2*p][0], g00 = c_first[0][9-2*p][1];
          const float f01 = c_first[0][8-2*p][0], g01 = c_first[0][8-2*p][1];
          const float f10 = c_first[1][9-2*p][0], g10 = c_first[1][9-2*p][1];
          const float f11 = c_first[1][8-2*p][0], g11 = c_first[1][8-2*p][1];
          o00 += f00*wla0e[kk] + g00*wha0e[kk] + f10*wla1e[kk] + g10*wha1e[kk];
          o01 += f00*wla0o[kk] + g00*wha0o[kk] + f10*wla1o[kk] + g10*wha1o[kk];
          o10 += f01*wla0e[kk] + g01*wha0e[kk] + f11*wla1e[kk] + g11*wha1e[kk];
          o11 += f01*wla0o[kk] + g01*wha0o[kk] + f11*wla1o[kk] + g11*wha1o[kk];
        }
        float* q = outb + (2*s) * ROWO + (2*t) * C + c;
        q[0]        = o00;   // 0.5 folded into staging
        q[C]        = o01;
        q[ROWO]     = o10;
        q[ROWO + C] = o11;
      }

      if (i < NI - 1) {
        S2_PIN();                         // loads may not sink below here
        S2_WRITE(nxt);                    // vmcnt wait lands here
      }
      __syncthreads();
      { float4* tmp = cur; cur = nxt; nxt = tmp; }
    }
  }
#undef S2_LOAD
#undef S2_PIN
#undef S2_WRITE
}

extern "C" void kernel_launch(void* const* d_in, const int* in_sizes, int n_in,
                              void* d_out, int out_size, void* d_ws, size_t ws_size,
                              hipStream_t stream) {
  const float* highs0 = (const float*)d_in[0];  // (2,2,3,16,256,256,3)
  const float* highs1 = (const float*)d_in[1];  // (2,2,3,16,128,128,3)
  const float* lows   = (const float*)d_in[2];  // (2,2,16,128,128,3)
  float* out = (float*)d_out;                   // (16,512,512,3)
  float* lo2 = (float*)d_ws;                    // 50.3 MB

  dim3 b1(128), g1(3, 8, 64);
  hipLaunchKernelGGL(idtcwt_stage1, g1, b1, 0, stream, lows, highs1, lo2);

  dim3 b2(256), g2(3, 16, 16);
  hipLaunchKernelGGL(idtcwt_stage2, g2, b2, 0, stream, lo2, highs0, out);
}